// Round 8
// baseline (412.041 us; speedup 1.0000x reference)
//
#include <hip/hip_runtime.h>
#include <math.h>

#define NT 2560
#define DF 32
#define NB 4
#define SELF_EPS 0.5f
#define MS 8                 // m-split across blocks
#define MROWS (NT / MS)      // 320 m rows per block
#define MT 64                // m tile
#define MITERS (MROWS / MT)  // 5
#define TN 64                // n rows per block (4 waves x 16)
#define NBK (NT / TN)        // 40 n-tiles
#define SG_FRAG (MITERS * 2 * 64 * 8)   // 5120 shorts per (block,wave) stream

typedef __attribute__((ext_vector_type(8))) short bf16x8;
typedef __attribute__((ext_vector_type(4))) float f32x4;

// hardware packed fp32->bf16 (RNE): 1 inst replaces ~11
__device__ __forceinline__ unsigned pk2(float a, float b) {
    unsigned r;
    asm("v_cvt_pk_bf16_f32 %0, %1, %2" : "=v"(r) : "v"(a), "v"(b));
    return r;
}

__device__ __forceinline__ float fast_rcp(float x) {
#if __has_builtin(__builtin_amdgcn_rcpf)
    return __builtin_amdgcn_rcpf(x);
#else
    return 1.0f / x;
#endif
}

// tanh(relu(x)) = 1 - 2/(exp(2x)+1) for x>=0
__device__ __forceinline__ float tanh_relu(float x) {
    x = fmaxf(x, 0.0f);
    float e = __expf(x + x);
    return 1.0f - 2.0f * fast_rcp(e + 1.0f);
}

// device-coherent atomic load (bypasses non-coherent per-XCD L2)
__device__ __forceinline__ float aload(const float* p) {
    return __hip_atomic_load(p, __ATOMIC_RELAXED, __HIP_MEMORY_SCOPE_AGENT);
}

// ---------------------------------------------------------------------------
// prep: blocks [0,640) zero agg1+agg2 (2.62 MB); block 0 zeros ALL 320 tickets
// (R6 bug: t<320 with 256 threads left 64 tickets poisoned).
// blocks [640,960): X fp32 -> Xb bf16 [B][NT][32] + XT bf16 [B][32][NT].
// ---------------------------------------------------------------------------
__global__ __launch_bounds__(256, 4)
void prep(const float* __restrict__ X, float* __restrict__ aggz,
          int* __restrict__ cnt,
          unsigned short* __restrict__ Xb, unsigned short* __restrict__ XT)
{
    const int bid = blockIdx.x, t = threadIdx.x;
    if (bid < 640) {
        f32x4 z = {0.f, 0.f, 0.f, 0.f};
        ((f32x4*)aggz)[(size_t)bid * 256 + t] = z;
        if (bid == 0) {
            for (int i = t; i < 2 * NB * NBK; i += 256) cnt[i] = 0;
        }
        return;
    }
    __shared__ float sT[32][33];
    const int tile = bid - 640;
    const int b = tile / 80, n0 = (tile % 80) * 32;
    const int row = t >> 3, c4 = (t & 7) * 4;
    const size_t rbase = ((size_t)(b * NT + n0 + row)) * DF + c4;
    const float4 v = *(const float4*)(X + rbase);
    unsigned p0 = pk2(v.x, v.y);
    unsigned p1 = pk2(v.z, v.w);
    *(uint2*)(Xb + rbase) = make_uint2(p0, p1);
    sT[row][c4 + 0] = v.x; sT[row][c4 + 1] = v.y;
    sT[row][c4 + 2] = v.z; sT[row][c4 + 3] = v.w;
    __syncthreads();
    const int d = t >> 3, nq = (t & 7) * 4;
    unsigned q0 = pk2(sT[nq + 0][d], sT[nq + 1][d]);
    unsigned q1 = pk2(sT[nq + 2][d], sT[nq + 3][d]);
    *(uint2*)(XT + ((size_t)(b * DF + d)) * NT + n0 + nq) = make_uint2(q0, q1);
}

// ---------------------------------------------------------------------------
// winner epilogue: 64 rows in two 32-row passes; agg read via coherent
// atomic loads (already fully summed by device-scope atomics).
// ---------------------------------------------------------------------------
__device__ __forceinline__ void winner_epi(
    float (*sW)[33], float (*sN)[33], float (*sH)[33], float (*sA)[33],
    float (*sT)[33],
    const int t, const int b, const int n0,
    const float* __restrict__ Hin, const float* __restrict__ agg,
    const float* __restrict__ Wsl, const float* __restrict__ Wnl,
    const float* __restrict__ bl,
    float* __restrict__ Hout, unsigned short* __restrict__ HTout)
{
    const size_t xbase = (size_t)b * NT * DF;
    const size_t tbase = (size_t)b * DF * NT;
    const int row = t >> 3, c4 = (t & 7) * 4;
    {
        const float4 w0 = *(const float4*)(Wsl + row * DF + c4);
        const float4 w1 = *(const float4*)(Wnl + row * DF + c4);
        sW[row][c4+0]=w0.x; sW[row][c4+1]=w0.y; sW[row][c4+2]=w0.z; sW[row][c4+3]=w0.w;
        sN[row][c4+0]=w1.x; sN[row][c4+1]=w1.y; sN[row][c4+2]=w1.z; sN[row][c4+3]=w1.w;
    }
    const float bb0 = bl[c4+0], bb1 = bl[c4+1], bb2 = bl[c4+2], bb3 = bl[c4+3];

    #pragma unroll
    for (int p = 0; p < 2; ++p) {
        const int r0 = n0 + p * 32;
        const size_t rb = xbase + (size_t)(r0 + row) * DF + c4;
        const float4 hv = *(const float4*)(Hin + rb);
        const float a0 = aload(agg + rb + 0), a1 = aload(agg + rb + 1);
        const float a2 = aload(agg + rb + 2), a3 = aload(agg + rb + 3);
        __syncthreads();                    // prev pass LDS reads done
        sH[row][c4+0]=hv.x; sH[row][c4+1]=hv.y; sH[row][c4+2]=hv.z; sH[row][c4+3]=hv.w;
        sA[row][c4+0]=a0;   sA[row][c4+1]=a1;   sA[row][c4+2]=a2;   sA[row][c4+3]=a3;
        __syncthreads();
        float4 z = make_float4(bb0, bb1, bb2, bb3);
        #pragma unroll
        for (int k = 0; k < DF; ++k) {
            const float hk = sH[row][k], ak = sA[row][k];
            z.x += hk * sW[k][c4+0] + ak * sN[k][c4+0];
            z.y += hk * sW[k][c4+1] + ak * sN[k][c4+1];
            z.z += hk * sW[k][c4+2] + ak * sN[k][c4+2];
            z.w += hk * sW[k][c4+3] + ak * sN[k][c4+3];
        }
        z.x = z.x > 0.f ? z.x : __expf(z.x) - 1.f;
        z.y = z.y > 0.f ? z.y : __expf(z.y) - 1.f;
        z.z = z.z > 0.f ? z.z : __expf(z.z) - 1.f;
        z.w = z.w > 0.f ? z.w : __expf(z.w) - 1.f;
        *(float4*)(Hout + rb) = z;
        if (HTout != nullptr) {
            sT[row][c4+0]=z.x; sT[row][c4+1]=z.y; sT[row][c4+2]=z.z; sT[row][c4+3]=z.w;
        }
        __syncthreads();
        if (HTout != nullptr) {             // H1T: [B][32][NT] bf16
            const int d = t >> 3, nq = (t & 7) * 4;
            unsigned q0 = pk2(sT[nq+0][d], sT[nq+1][d]);
            unsigned q1 = pk2(sT[nq+2][d], sT[nq+3][d]);
            *(uint2*)(HTout + tbase + (size_t)d * NT + r0 + nq) = make_uint2(q0, q1);
        }
    }
}

// ---------------------------------------------------------------------------
// main (layer 1): R7-proven structure; partials atomicAdd into agg1; ticket
// winner runs the layer-1 epilogue inline (h1 + H1T). S-frags streamed to Sg.
// ---------------------------------------------------------------------------
union MLDS {
    struct {
        unsigned short XmL[64 * 40];       // pad 40 (80B rows)
        unsigned short HtL[32 * 72];       // pad 72 (144B rows)
        unsigned short Ss[4 * 16 * 72];    // per-wave 16n x 64m
    } m;                                   // 18944 B
    struct { float sW[32][33], sN[32][33], sH[32][33], sA[32][33], sT[32][33]; } e;  // 21120 B
};

__global__ __launch_bounds__(256, 4)
void gsage_main(const unsigned short* __restrict__ Xb,  // [B][NT][32] bf16
                const unsigned short* __restrict__ HT,  // [B][32][NT] bf16
                float* __restrict__ agg,                // [B][NT][32] fp32 (zeroed)
                unsigned short* __restrict__ Sg,        // S-frag stream
                int* __restrict__ cnt,                  // [B*NBK] tickets
                const float* __restrict__ X,            // epi self-term (fp32)
                const float* __restrict__ Wsl, const float* __restrict__ Wnl,
                const float* __restrict__ bl,
                float* __restrict__ Hout, unsigned short* __restrict__ HTout)
{
    __shared__ MLDS L;
    __shared__ int wflag;

    const int t = threadIdx.x;
    const int w = t >> 6, lane = t & 63;
    const int q = lane >> 4, c = lane & 15;
    const int n0 = blockIdx.x * TN;
    const int mbase = blockIdx.y * MROWS;
    const int b = blockIdx.z;

    const size_t xbase = (size_t)b * NT * DF;
    const size_t tbase = (size_t)b * DF * NT;

    const bf16x8 bfn = *(const bf16x8*)(Xb + xbase + (size_t)(n0 + w * 16 + c) * DF + q * 8);

    f32x4 acc0 = {0.f, 0.f, 0.f, 0.f};
    f32x4 acc1 = {0.f, 0.f, 0.f, 0.f};

    const int xrow = t >> 2, xseg = t & 3;   // Xm stage: 64 rows, 4 x 16B
    const int hrow = t >> 3, hseg = t & 7;   // HT stage: 32 rows, 8 x 16B

    uint4 xv = *(const uint4*)(Xb + xbase + (size_t)(mbase + xrow) * DF + xseg * 8);
    uint4 hv = *(const uint4*)(HT + tbase + (size_t)hrow * NT + mbase + hseg * 8);

    const int n_g = n0 + w * 16 + c;
    unsigned short* SsW = L.m.Ss + w * (16 * 72);
    unsigned short* Sgw = Sg
        + ((((size_t)b * MS + blockIdx.y) * NBK + blockIdx.x) * 4 + w) * (size_t)SG_FRAG
        + (size_t)lane * 8;

    for (int it = 0; it < MITERS; ++it) {
        const int m0 = mbase + it * MT;
        __syncthreads();                       // prior iter done reading LDS
        *(uint4*)(L.m.XmL + xrow * 40 + xseg * 8) = xv;
        *(uint4*)(L.m.HtL + hrow * 72 + hseg * 8) = hv;
        if (it + 1 < MITERS) {
            const int m1 = m0 + MT;
            xv = *(const uint4*)(Xb + xbase + (size_t)(m1 + xrow) * DF + xseg * 8);
            hv = *(const uint4*)(HT + tbase + (size_t)hrow * NT + m1 + hseg * 8);
        }
        __syncthreads();                       // tiles staged

        if (m0 == n0) {
            #pragma unroll
            for (int t4 = 0; t4 < 4; ++t4) {
                const bf16x8 af = *(const bf16x8*)(L.m.XmL + (t4 * 16 + c) * 40 + q * 8);
                const f32x4 zero = {0.f, 0.f, 0.f, 0.f};
                f32x4 st = __builtin_amdgcn_mfma_f32_16x16x32_bf16(af, bfn, zero, 0, 0, 0);
                const int m2 = m0 + t4 * 16 + q * 4;
                float v0 = tanh_relu(st[0]); if (n_g == m2 + 0) v0 += SELF_EPS;
                float v1 = tanh_relu(st[1]); if (n_g == m2 + 1) v1 += SELF_EPS;
                float v2 = tanh_relu(st[2]); if (n_g == m2 + 2) v2 += SELF_EPS;
                float v3 = tanh_relu(st[3]); if (n_g == m2 + 3) v3 += SELF_EPS;
                unsigned p0 = pk2(v0, v1);
                unsigned p1 = pk2(v2, v3);
                *(uint2*)(SsW + c * 72 + t4 * 16 + q * 4) = make_uint2(p0, p1);
            }
        } else {
            #pragma unroll
            for (int t4 = 0; t4 < 4; ++t4) {
                const bf16x8 af = *(const bf16x8*)(L.m.XmL + (t4 * 16 + c) * 40 + q * 8);
                const f32x4 zero = {0.f, 0.f, 0.f, 0.f};
                f32x4 st = __builtin_amdgcn_mfma_f32_16x16x32_bf16(af, bfn, zero, 0, 0, 0);
                unsigned p0 = pk2(tanh_relu(st[0]), tanh_relu(st[1]));
                unsigned p1 = pk2(tanh_relu(st[2]), tanh_relu(st[3]));
                *(uint2*)(SsW + c * 72 + t4 * 16 + q * 4) = make_uint2(p0, p1);
            }
        }
        asm volatile("s_waitcnt lgkmcnt(0)" ::: "memory");

        #pragma unroll
        for (int kc = 0; kc < 2; ++kc) {
            const bf16x8 sf = *(const bf16x8*)(SsW + c * 72 + kc * 32 + q * 8);
            *(uint4*)(Sgw + (size_t)(it * 2 + kc) * (64 * 8)) = __builtin_bit_cast(uint4, sf);
            const bf16x8 h0 = *(const bf16x8*)(L.m.HtL + c * 72 + kc * 32 + q * 8);
            const bf16x8 h1f = *(const bf16x8*)(L.m.HtL + (16 + c) * 72 + kc * 32 + q * 8);
            acc0 = __builtin_amdgcn_mfma_f32_16x16x32_bf16(sf, h0, acc0, 0, 0, 0);
            acc1 = __builtin_amdgcn_mfma_f32_16x16x32_bf16(sf, h1f, acc1, 0, 0, 0);
        }
    }

    // partials: device-scope atomics (R0: perf-neutral)
    float* ap = agg + xbase + (size_t)(n0 + w * 16 + q * 4) * DF + c;
    #pragma unroll
    for (int r = 0; r < 4; ++r) {
        atomicAdd(ap + (size_t)r * DF, acc0[r]);
        atomicAdd(ap + (size_t)r * DF + 16, acc1[r]);
    }

    // ---- atomic ticket: last of MS blocks for this (b, n-tile) runs epi ----
    __threadfence();                           // release: adds visible before ticket
    __syncthreads();
    if (t == 0) wflag = (atomicAdd(&cnt[b * NBK + blockIdx.x], 1) == MS - 1);
    __syncthreads();
    if (!wflag) return;
    __threadfence();                           // acquire

    winner_epi(L.e.sW, L.e.sN, L.e.sH, L.e.sA, L.e.sT,
               t, b, n0, X, agg, Wsl, Wnl, bl, Hout, HTout);
}

// ---------------------------------------------------------------------------
// layer-2 agg: replay stored S fragments (prefetched), stage H1T, 4 MFMAs/iter;
// atomicAdd into agg2; ticket winner runs epilogue 2 -> out.
// ---------------------------------------------------------------------------
union ALDS {
    struct { unsigned short HtL[32 * 72]; } m;                       // 4608 B
    struct { float sW[32][33], sN[32][33], sH[32][33], sA[32][33]; } e;  // 16896 B
};

__global__ __launch_bounds__(256, 4)
void gsage_agg(const unsigned short* __restrict__ Sg,
               const unsigned short* __restrict__ HT,  // [B][32][NT] bf16
               float* __restrict__ agg,                // [B][NT][32] fp32 (zeroed)
               int* __restrict__ cnt,
               const float* __restrict__ Hin,          // h1 (fp32)
               const float* __restrict__ Wsl, const float* __restrict__ Wnl,
               const float* __restrict__ bl,
               float* __restrict__ out)
{
    __shared__ ALDS L;
    __shared__ int wflag;

    const int t = threadIdx.x;
    const int w = t >> 6, lane = t & 63;
    const int q = lane >> 4, c = lane & 15;
    const int n0 = blockIdx.x * TN;
    const int mbase = blockIdx.y * MROWS;
    const int b = blockIdx.z;
    const size_t tbase = (size_t)b * DF * NT;
    const size_t xbase = (size_t)b * NT * DF;

    const int hrow = t >> 3, hseg = t & 7;
    uint4 hv = *(const uint4*)(HT + tbase + (size_t)hrow * NT + mbase + hseg * 8);

    const unsigned short* Sp = Sg
        + ((((size_t)b * MS + blockIdx.y) * NBK + blockIdx.x) * 4 + w) * (size_t)SG_FRAG
        + (size_t)lane * 8;

    bf16x8 sf0 = *(const bf16x8*)(Sp);
    bf16x8 sf1 = *(const bf16x8*)(Sp + 64 * 8);

    f32x4 acc0 = {0.f, 0.f, 0.f, 0.f};
    f32x4 acc1 = {0.f, 0.f, 0.f, 0.f};

    for (int it = 0; it < MITERS; ++it) {
        __syncthreads();                       // prior iter done reading HtL
        *(uint4*)(L.m.HtL + hrow * 72 + hseg * 8) = hv;
        bf16x8 nsf0, nsf1;
        if (it + 1 < MITERS) {
            hv = *(const uint4*)(HT + tbase + (size_t)hrow * NT
                                 + (mbase + (it + 1) * MT) + hseg * 8);
            nsf0 = *(const bf16x8*)(Sp + (size_t)((it + 1) * 2 + 0) * (64 * 8));
            nsf1 = *(const bf16x8*)(Sp + (size_t)((it + 1) * 2 + 1) * (64 * 8));
        }
        __syncthreads();                       // tile staged

        const bf16x8 h00 = *(const bf16x8*)(L.m.HtL + c * 72 + 0 * 32 + q * 8);
        const bf16x8 h01 = *(const bf16x8*)(L.m.HtL + (16 + c) * 72 + 0 * 32 + q * 8);
        acc0 = __builtin_amdgcn_mfma_f32_16x16x32_bf16(sf0, h00, acc0, 0, 0, 0);
        acc1 = __builtin_amdgcn_mfma_f32_16x16x32_bf16(sf0, h01, acc1, 0, 0, 0);
        const bf16x8 h10 = *(const bf16x8*)(L.m.HtL + c * 72 + 1 * 32 + q * 8);
        const bf16x8 h11 = *(const bf16x8*)(L.m.HtL + (16 + c) * 72 + 1 * 32 + q * 8);
        acc0 = __builtin_amdgcn_mfma_f32_16x16x32_bf16(sf1, h10, acc0, 0, 0, 0);
        acc1 = __builtin_amdgcn_mfma_f32_16x16x32_bf16(sf1, h11, acc1, 0, 0, 0);

        if (it + 1 < MITERS) { sf0 = nsf0; sf1 = nsf1; }
    }

    float* ap = agg + xbase + (size_t)(n0 + w * 16 + q * 4) * DF + c;
    #pragma unroll
    for (int r = 0; r < 4; ++r) {
        atomicAdd(ap + (size_t)r * DF, acc0[r]);
        atomicAdd(ap + (size_t)r * DF + 16, acc1[r]);
    }

    __threadfence();
    __syncthreads();
    if (t == 0) wflag = (atomicAdd(&cnt[b * NBK + blockIdx.x], 1) == MS - 1);
    __syncthreads();
    if (!wflag) return;
    __threadfence();

    winner_epi(L.e.sW, L.e.sN, L.e.sH, L.e.sA, (float(*)[33])nullptr,
               t, b, n0, Hin, agg, Wsl, Wnl, bl, out, nullptr);
}

extern "C" void kernel_launch(void* const* d_in, const int* in_sizes, int n_in,
                              void* d_out, int out_size, void* d_ws, size_t ws_size,
                              hipStream_t stream) {
    const float* X  = (const float*)d_in[0];
    const float* Ws = (const float*)d_in[1];   // [2][32][32]
    const float* Wn = (const float*)d_in[2];   // [2][32][32]
    const float* bv = (const float*)d_in[3];   // [2][32]
    float* out = (float*)d_out;

    char* ws = (char*)d_ws;
    float* agg1 = (float*)ws;                                // 1,310,720 B
    float* agg2 = agg1 + (size_t)NB * NT * DF;               // 1,310,720 B (contig zero region)
    int*   cnt  = (int*)(ws + 2621440);                      // 320 ints (cnt1 + cnt2)
    float* h1   = (float*)(ws + 2625536);                    // 1,310,720 B
    unsigned short* Xb  = (unsigned short*)(ws + 3936256);   // 655,360 B
    unsigned short* XT  = Xb + (size_t)NB * NT * DF;         // 655,360 B
    unsigned short* H1T = XT + (size_t)NB * NT * DF;         // 655,360 B
    unsigned short* Sg  = H1T + (size_t)NB * NT * DF;        // 52,428,800 B (~58.3 MB total)

    prep<<<960, 256, 0, stream>>>(X, agg1, cnt, Xb, XT);

    dim3 g(NBK, MS, NB);   // 40 x 8 x 4 = 1280 blocks
    gsage_main<<<g, 256, 0, stream>>>(Xb, XT, agg1, Sg, cnt, X, Ws, Wn, bv, h1, H1T);
    gsage_agg<<<g, 256, 0, stream>>>(Sg, H1T, agg2, cnt + NB * NBK, h1,
                                     Ws + DF * DF, Wn + DF * DF, bv + DF, out);
}

// Round 9
// 112.884 us; speedup vs baseline: 3.6501x; 3.6501x over previous
//
#include <hip/hip_runtime.h>
#include <math.h>

#define NT 2560
#define DF 32
#define NB 4
#define SELF_EPS 0.5f
#define MS 8                 // m-split across blocks
#define MROWS (NT / MS)      // 320 m rows per block
#define MT 64                // m tile
#define MITERS (MROWS / MT)  // 5
#define TN 64                // n rows per block (4 waves x 16)
#define NBK (NT / TN)        // 40 n-blocks

typedef __attribute__((ext_vector_type(8))) short bf16x8;
typedef __attribute__((ext_vector_type(4))) float f32x4;

// hardware packed fp32->bf16 (RNE): 1 inst replaces ~11
__device__ __forceinline__ unsigned pk2(float a, float b) {
    unsigned r;
    asm("v_cvt_pk_bf16_f32 %0, %1, %2" : "=v"(r) : "v"(a), "v"(b));
    return r;
}

__device__ __forceinline__ float fast_rcp(float x) {
#if __has_builtin(__builtin_amdgcn_rcpf)
    return __builtin_amdgcn_rcpf(x);
#else
    return 1.0f / x;
#endif
}

// tanh(relu(x)) = 1 - 2/(exp(2x)+1) for x>=0
__device__ __forceinline__ float tanh_relu(float x) {
    x = fmaxf(x, 0.0f);
    float e = __expf(x + x);
    return 1.0f - 2.0f * fast_rcp(e + 1.0f);
}

// ---------------------------------------------------------------------------
// prep: X fp32 -> Xb bf16 row-major [B][NT][32] and XT bf16 [B][32][NT].
// ---------------------------------------------------------------------------
__global__ __launch_bounds__(256, 4)
void prep(const float* __restrict__ X,
          unsigned short* __restrict__ Xb, unsigned short* __restrict__ XT)
{
    const int t = threadIdx.x;
    __shared__ float sT[32][33];
    const int tile = blockIdx.x;
    const int b = tile / 80, n0 = (tile % 80) * 32;
    const int row = t >> 3, c4 = (t & 7) * 4;
    const size_t rbase = ((size_t)(b * NT + n0 + row)) * DF + c4;
    const float4 v = *(const float4*)(X + rbase);
    unsigned p0 = pk2(v.x, v.y);
    unsigned p1 = pk2(v.z, v.w);
    *(uint2*)(Xb + rbase) = make_uint2(p0, p1);
    sT[row][c4 + 0] = v.x; sT[row][c4 + 1] = v.y;
    sT[row][c4 + 2] = v.z; sT[row][c4 + 3] = v.w;
    __syncthreads();
    const int d = t >> 3, nq = (t & 7) * 4;
    unsigned q0 = pk2(sT[nq + 0][d], sT[nq + 1][d]);
    unsigned q1 = pk2(sT[nq + 2][d], sT[nq + 3][d]);
    *(uint2*)(XT + ((size_t)(b * DF + d)) * NT + n0 + nq) = make_uint2(q0, q1);
}

// ---------------------------------------------------------------------------
// main (layer 1): per block, n-tile 64 x m-slice 320. BARRIER-FREE:
// score A-frags (af) and agg B-frags (h0/h1) are per-lane 16B global reads
// from L2-resident Xb/HT (no XmL/HtL staging, no __syncthreads). Only the
// per-wave Ss cross-lane round-trip remains in LDS (wave-local lgkmcnt).
// S fragments streamed to Sg so layer 2 skips all score computation.
// ---------------------------------------------------------------------------
__global__ __launch_bounds__(256, 6)
void gsage_main(const unsigned short* __restrict__ Xb,  // [B][NT][32] bf16
                const unsigned short* __restrict__ HT,  // [B][32][NT] bf16
                float* __restrict__ P,                  // [MS][B][NT][32] fp32
                unsigned short* __restrict__ Sg)        // S-frag stream
{
    __shared__ unsigned short Ss[4 * 16 * 72];    // per-wave 16n x 64m (pad 72)

    const int t = threadIdx.x;
    const int w = t >> 6, lane = t & 63;
    const int q = lane >> 4, c = lane & 15;
    const int n0 = blockIdx.x * TN;
    const int mbase = blockIdx.y * MROWS;
    const int b = blockIdx.z;

    const size_t xbase = (size_t)b * NT * DF;   // elem offsets (row-major)
    const size_t tbase = (size_t)b * DF * NT;   // elem offsets (transposed)

    // score B-frag: Xn[n = n0+w*16+c][k = q*8 .. q*8+7], constant over m-loop
    const bf16x8 bfn = *(const bf16x8*)(Xb + xbase + (size_t)(n0 + w * 16 + c) * DF + q * 8);

    f32x4 acc0 = {0.f, 0.f, 0.f, 0.f};
    f32x4 acc1 = {0.f, 0.f, 0.f, 0.f};

    const int n_g = n0 + w * 16 + c;
    unsigned short* SsW = Ss + w * (16 * 72);

    // per-(block,wave,lane) S-frag stream base: [b][my][nb][w][it][kc][lane][8]
    unsigned short* Sgw = Sg
        + ((((size_t)b * MS + blockIdx.y) * NBK + blockIdx.x) * 4 + w)
          * ((size_t)MITERS * 2 * 64 * 8)
        + (size_t)lane * 8;

    for (int it = 0; it < MITERS; ++it) {
        const int m0 = mbase + it * MT;
        // wave-local: prior iter's Ss reads drained before overwrite
        asm volatile("s_waitcnt lgkmcnt(0)" ::: "memory");

        // ---- scores: St[m][n] tiles; lane holds S[n=c][m = t4*16+q*4+r] ----
        if (m0 == n0) {
            #pragma unroll
            for (int t4 = 0; t4 < 4; ++t4) {
                const bf16x8 af = *(const bf16x8*)(Xb + xbase
                    + (size_t)(m0 + t4 * 16 + c) * DF + q * 8);
                const f32x4 zero = {0.f, 0.f, 0.f, 0.f};
                f32x4 st = __builtin_amdgcn_mfma_f32_16x16x32_bf16(af, bfn, zero, 0, 0, 0);
                const int m2 = m0 + t4 * 16 + q * 4;
                float v0 = tanh_relu(st[0]); if (n_g == m2 + 0) v0 += SELF_EPS;
                float v1 = tanh_relu(st[1]); if (n_g == m2 + 1) v1 += SELF_EPS;
                float v2 = tanh_relu(st[2]); if (n_g == m2 + 2) v2 += SELF_EPS;
                float v3 = tanh_relu(st[3]); if (n_g == m2 + 3) v3 += SELF_EPS;
                unsigned p0 = pk2(v0, v1);
                unsigned p1 = pk2(v2, v3);
                *(uint2*)(SsW + c * 72 + t4 * 16 + q * 4) = make_uint2(p0, p1);
            }
        } else {
            #pragma unroll
            for (int t4 = 0; t4 < 4; ++t4) {
                const bf16x8 af = *(const bf16x8*)(Xb + xbase
                    + (size_t)(m0 + t4 * 16 + c) * DF + q * 8);
                const f32x4 zero = {0.f, 0.f, 0.f, 0.f};
                f32x4 st = __builtin_amdgcn_mfma_f32_16x16x32_bf16(af, bfn, zero, 0, 0, 0);
                unsigned p0 = pk2(tanh_relu(st[0]), tanh_relu(st[1]));
                unsigned p1 = pk2(tanh_relu(st[2]), tanh_relu(st[3]));
                *(uint2*)(SsW + c * 72 + t4 * 16 + q * 4) = make_uint2(p0, p1);
            }
        }
        // cross-lane S visibility within the wave: drain LDS writes
        asm volatile("s_waitcnt lgkmcnt(0)" ::: "memory");

        // ---- agg: acc[n][d] += S[n][m] * H[m][d], K=64 in 2 chunks ----
        #pragma unroll
        for (int kc = 0; kc < 2; ++kc) {
            const bf16x8 sf = *(const bf16x8*)(SsW + c * 72 + kc * 32 + q * 8);
            // stream the A-layout fragment out for layer 2 (coalesced 16B/lane)
            *(uint4*)(Sgw + (size_t)(it * 2 + kc) * (64 * 8)) = __builtin_bit_cast(uint4, sf);
            const bf16x8 h0 = *(const bf16x8*)(HT + tbase
                + (size_t)c * NT + m0 + kc * 32 + q * 8);
            const bf16x8 h1 = *(const bf16x8*)(HT + tbase
                + (size_t)(16 + c) * NT + m0 + kc * 32 + q * 8);
            acc0 = __builtin_amdgcn_mfma_f32_16x16x32_bf16(sf, h0, acc0, 0, 0, 0);
            acc1 = __builtin_amdgcn_mfma_f32_16x16x32_bf16(sf, h1, acc1, 0, 0, 0);
        }
    }

    float* ap = P + ((size_t)blockIdx.y * NB + b) * NT * DF
                  + (size_t)(n0 + w * 16 + q * 4) * DF + c;
    #pragma unroll
    for (int r = 0; r < 4; ++r) {
        ap[(size_t)r * DF] = acc0[r];
        ap[(size_t)r * DF + 16] = acc1[r];
    }
}

// ---------------------------------------------------------------------------
// layer-2 agg: NO LDS, NO barriers — pure unrolled stream: S-frags from Sg
// (coalesced), B-frags per-lane from L2-resident H1T, 4 MFMAs/iter.
// ---------------------------------------------------------------------------
__global__ __launch_bounds__(256, 8)
void gsage_agg(const unsigned short* __restrict__ Sg,
               const unsigned short* __restrict__ HT,  // [B][32][NT] bf16
               float* __restrict__ P)                  // [MS][B][NT][32] fp32
{
    const int t = threadIdx.x;
    const int w = t >> 6, lane = t & 63;
    const int q = lane >> 4, c = lane & 15;
    const int n0 = blockIdx.x * TN;
    const int mbase = blockIdx.y * MROWS;
    const int b = blockIdx.z;
    const size_t tbase = (size_t)b * DF * NT;

    const unsigned short* Sp = Sg
        + ((((size_t)b * MS + blockIdx.y) * NBK + blockIdx.x) * 4 + w)
          * ((size_t)MITERS * 2 * 64 * 8)
        + (size_t)lane * 8;

    f32x4 acc0 = {0.f, 0.f, 0.f, 0.f};
    f32x4 acc1 = {0.f, 0.f, 0.f, 0.f};

    #pragma unroll
    for (int it = 0; it < MITERS; ++it) {
        const int m0 = mbase + it * MT;
        #pragma unroll
        for (int kc = 0; kc < 2; ++kc) {
            const bf16x8 sf = *(const bf16x8*)(Sp + (size_t)(it * 2 + kc) * (64 * 8));
            const bf16x8 h0 = *(const bf16x8*)(HT + tbase
                + (size_t)c * NT + m0 + kc * 32 + q * 8);
            const bf16x8 h1 = *(const bf16x8*)(HT + tbase
                + (size_t)(16 + c) * NT + m0 + kc * 32 + q * 8);
            acc0 = __builtin_amdgcn_mfma_f32_16x16x32_bf16(sf, h0, acc0, 0, 0, 0);
            acc1 = __builtin_amdgcn_mfma_f32_16x16x32_bf16(sf, h1, acc1, 0, 0, 0);
        }
    }

    float* ap = P + ((size_t)blockIdx.y * NB + b) * NT * DF
                  + (size_t)(n0 + w * 16 + q * 4) * DF + c;
    #pragma unroll
    for (int r = 0; r < 4; ++r) {
        ap[(size_t)r * DF] = acc0[r];
        ap[(size_t)r * DF + 16] = acc1[r];
    }
}

// ---------------------------------------------------------------------------
// epilogue: agg = sum of 8 m-slice partials; Hout = elu(Hin*Ws + agg*Wn + b);
// optionally emit Hout^T bf16.
// ---------------------------------------------------------------------------
__global__ __launch_bounds__(256, 4)
void gsage_epi(const float* __restrict__ Hin, const float* __restrict__ P,
               const float* __restrict__ Wsl, const float* __restrict__ Wnl,
               const float* __restrict__ bl,
               float* __restrict__ Hout, unsigned short* __restrict__ HTout)
{
    __shared__ float sW[32][33], sN[32][33], sH[32][36], sA[32][36], sT[32][33];
    const int t = threadIdx.x;
    const int n0 = blockIdx.x * 32;
    const int b = blockIdx.y;
    const int row = t >> 3, c4 = (t & 7) * 4;
    const size_t rb = ((size_t)(b * NT + n0 + row)) * DF + c4;
    const float4 hv = *(const float4*)(Hin + rb);
    const size_t pstride = (size_t)NB * NT * DF;
    float4 av = *(const float4*)(P + rb);
    #pragma unroll
    for (int s = 1; s < MS; ++s) {
        const float4 pv = *(const float4*)(P + (size_t)s * pstride + rb);
        av.x += pv.x; av.y += pv.y; av.z += pv.z; av.w += pv.w;
    }
    const float4 w0 = *(const float4*)(Wsl + row * DF + c4);
    const float4 w1 = *(const float4*)(Wnl + row * DF + c4);
    sH[row][c4+0]=hv.x; sH[row][c4+1]=hv.y; sH[row][c4+2]=hv.z; sH[row][c4+3]=hv.w;
    sA[row][c4+0]=av.x; sA[row][c4+1]=av.y; sA[row][c4+2]=av.z; sA[row][c4+3]=av.w;
    sW[row][c4+0]=w0.x; sW[row][c4+1]=w0.y; sW[row][c4+2]=w0.z; sW[row][c4+3]=w0.w;
    sN[row][c4+0]=w1.x; sN[row][c4+1]=w1.y; sN[row][c4+2]=w1.z; sN[row][c4+3]=w1.w;
    __syncthreads();

    float4 z = make_float4(bl[c4+0], bl[c4+1], bl[c4+2], bl[c4+3]);
    #pragma unroll
    for (int k = 0; k < DF; ++k) {
        const float hk = sH[row][k], ak = sA[row][k];
        z.x += hk * sW[k][c4+0] + ak * sN[k][c4+0];
        z.y += hk * sW[k][c4+1] + ak * sN[k][c4+1];
        z.z += hk * sW[k][c4+2] + ak * sN[k][c4+2];
        z.w += hk * sW[k][c4+3] + ak * sN[k][c4+3];
    }
    z.x = z.x > 0.f ? z.x : __expf(z.x) - 1.f;
    z.y = z.y > 0.f ? z.y : __expf(z.y) - 1.f;
    z.z = z.z > 0.f ? z.z : __expf(z.z) - 1.f;
    z.w = z.w > 0.f ? z.w : __expf(z.w) - 1.f;
    *(float4*)(Hout + rb) = z;

    if (HTout != nullptr) {
        sT[row][c4+0]=z.x; sT[row][c4+1]=z.y; sT[row][c4+2]=z.z; sT[row][c4+3]=z.w;
        __syncthreads();
        const int d = t >> 3, nq = (t & 7) * 4;
        unsigned q0 = pk2(sT[nq+0][d], sT[nq+1][d]);
        unsigned q1 = pk2(sT[nq+2][d], sT[nq+3][d]);
        *(uint2*)(HTout + ((size_t)(b * DF + d)) * NT + n0 + nq) = make_uint2(q0, q1);
    }
}

extern "C" void kernel_launch(void* const* d_in, const int* in_sizes, int n_in,
                              void* d_out, int out_size, void* d_ws, size_t ws_size,
                              hipStream_t stream) {
    const float* X  = (const float*)d_in[0];
    const float* Ws = (const float*)d_in[1];   // [2][32][32]
    const float* Wn = (const float*)d_in[2];   // [2][32][32]
    const float* bv = (const float*)d_in[3];   // [2][32]
    float* out = (float*)d_out;

    char* ws = (char*)d_ws;
    float* P  = (float*)ws;                                  // 10,485,760 B
    float* h1 = P + (size_t)MS * NB * NT * DF;               // 1,310,720 B
    unsigned short* Xb  = (unsigned short*)(ws + 11796480);  // 655,360 B
    unsigned short* XT  = Xb + (size_t)NB * NT * DF;         // 655,360 B
    unsigned short* H1T = XT + (size_t)NB * NT * DF;         // 655,360 B
    unsigned short* Sg  = H1T + (size_t)NB * NT * DF;        // 52,428,800 B

    prep<<<320, 256, 0, stream>>>(X, Xb, XT);

    dim3 g(NBK, MS, NB);   // 40 x 8 x 4 = 1280 blocks
    gsage_main<<<g, 256, 0, stream>>>(Xb, XT, P, Sg);
    gsage_epi<<<dim3(NT / 32, NB), 256, 0, stream>>>(X, P, Ws, Wn, bv, h1, H1T);
    gsage_agg<<<g, 256, 0, stream>>>(Sg, H1T, P);
    gsage_epi<<<dim3(NT / 32, NB), 256, 0, stream>>>(h1, P, Ws + DF * DF, Wn + DF * DF,
                                                     bv + DF, out, nullptr);
}

// Round 10
// 99.872 us; speedup vs baseline: 4.1257x; 1.1303x over previous
//
#include <hip/hip_runtime.h>
#include <math.h>

#define NT 2560
#define DF 32
#define NB 4
#define SELF_EPS 0.5f
#define MS 8                 // m-split across blocks
#define MROWS (NT / MS)      // 320 m rows per block
#define MT 64                // m tile
#define MITERS (MROWS / MT)  // 5
#define TN 64                // n rows per block (4 waves x 16)
#define NBK (NT / TN)        // 40 n-blocks

typedef __attribute__((ext_vector_type(8))) short bf16x8;
typedef __attribute__((ext_vector_type(4))) float f32x4;

// hardware packed fp32->bf16 (RNE): 1 inst replaces ~11
__device__ __forceinline__ unsigned pk2(float a, float b) {
    unsigned r;
    asm("v_cvt_pk_bf16_f32 %0, %1, %2" : "=v"(r) : "v"(a), "v"(b));
    return r;
}

__device__ __forceinline__ float fast_rcp(float x) {
#if __has_builtin(__builtin_amdgcn_rcpf)
    return __builtin_amdgcn_rcpf(x);
#else
    return 1.0f / x;
#endif
}

// tanh(relu(x)) = 1 - 2/(exp(2x)+1) for x>=0
__device__ __forceinline__ float tanh_relu(float x) {
    x = fmaxf(x, 0.0f);
    float e = __expf(x + x);
    return 1.0f - 2.0f * fast_rcp(e + 1.0f);
}

// ---------------------------------------------------------------------------
// prep: X fp32 -> Xb bf16 row-major [B][NT][32] and XT bf16 [B][32][NT].
// ---------------------------------------------------------------------------
__global__ __launch_bounds__(256, 4)
void prep(const float* __restrict__ X,
          unsigned short* __restrict__ Xb, unsigned short* __restrict__ XT)
{
    const int t = threadIdx.x;
    __shared__ float sT[32][33];
    const int tile = blockIdx.x;
    const int b = tile / 80, n0 = (tile % 80) * 32;
    const int row = t >> 3, c4 = (t & 7) * 4;
    const size_t rbase = ((size_t)(b * NT + n0 + row)) * DF + c4;
    const float4 v = *(const float4*)(X + rbase);
    unsigned p0 = pk2(v.x, v.y);
    unsigned p1 = pk2(v.z, v.w);
    *(uint2*)(Xb + rbase) = make_uint2(p0, p1);
    sT[row][c4 + 0] = v.x; sT[row][c4 + 1] = v.y;
    sT[row][c4 + 2] = v.z; sT[row][c4 + 3] = v.w;
    __syncthreads();
    const int d = t >> 3, nq = (t & 7) * 4;
    unsigned q0 = pk2(sT[nq + 0][d], sT[nq + 1][d]);
    unsigned q1 = pk2(sT[nq + 2][d], sT[nq + 3][d]);
    *(uint2*)(XT + ((size_t)(b * DF + d)) * NT + n0 + nq) = make_uint2(q0, q1);
}

// ---------------------------------------------------------------------------
// main (layer 1): R7-proven dataflow + double-buffered LDS staging
// (1 barrier/iter instead of 2) and launch_bounds(256,6) for more TLP.
// scores via mfma(A=Xm,B=Xn) -> per-wave S in LDS -> agg mfma; S fragments
// streamed to Sg so layer 2 skips all score computation.
// ---------------------------------------------------------------------------
__global__ __launch_bounds__(256, 6)
void gsage_main(const unsigned short* __restrict__ Xb,  // [B][NT][32] bf16
                const unsigned short* __restrict__ HT,  // [B][32][NT] bf16
                float* __restrict__ P,                  // [MS][B][NT][32] fp32
                unsigned short* __restrict__ Sg)        // S-frag stream
{
    __shared__ unsigned short XmL[2][64 * 40];    // dbuf, pad 40 (80B rows)
    __shared__ unsigned short HtL[2][32 * 72];    // dbuf, pad 72 (144B rows)
    __shared__ unsigned short Ss[4 * 16 * 72];    // per-wave 16n x 64m (pad 72)

    const int t = threadIdx.x;
    const int w = t >> 6, lane = t & 63;
    const int q = lane >> 4, c = lane & 15;
    const int n0 = blockIdx.x * TN;
    const int mbase = blockIdx.y * MROWS;
    const int b = blockIdx.z;

    const size_t xbase = (size_t)b * NT * DF;   // elem offsets (row-major)
    const size_t tbase = (size_t)b * DF * NT;   // elem offsets (transposed)

    // score B-frag: Xn[n = n0+w*16+c][k = q*8 .. q*8+7], constant over m-loop
    const bf16x8 bfn = *(const bf16x8*)(Xb + xbase + (size_t)(n0 + w * 16 + c) * DF + q * 8);

    f32x4 acc0 = {0.f, 0.f, 0.f, 0.f};
    f32x4 acc1 = {0.f, 0.f, 0.f, 0.f};

    const int xrow = t >> 2, xseg = t & 3;   // Xm stage: 64 rows, 4 x 16B
    const int hrow = t >> 3, hseg = t & 7;   // HT stage: 32 rows, 8 x 16B

    // prologue: stage tile 0 into buf 0; prefetch tile 1 into regs
    uint4 xv = *(const uint4*)(Xb + xbase + (size_t)(mbase + xrow) * DF + xseg * 8);
    uint4 hv = *(const uint4*)(HT + tbase + (size_t)hrow * NT + mbase + hseg * 8);
    *(uint4*)(XmL[0] + xrow * 40 + xseg * 8) = xv;
    *(uint4*)(HtL[0] + hrow * 72 + hseg * 8) = hv;
    xv = *(const uint4*)(Xb + xbase + (size_t)(mbase + MT + xrow) * DF + xseg * 8);
    hv = *(const uint4*)(HT + tbase + (size_t)hrow * NT + mbase + MT + hseg * 8);
    __syncthreads();                           // buf0 staged

    const int n_g = n0 + w * 16 + c;
    unsigned short* SsW = Ss + w * (16 * 72);

    // per-(block,wave,lane) S-frag stream base: [b][my][nb][w][it][kc][lane][8]
    unsigned short* Sgw = Sg
        + ((((size_t)b * MS + blockIdx.y) * NBK + blockIdx.x) * 4 + w)
          * ((size_t)MITERS * 2 * 64 * 8)
        + (size_t)lane * 8;

    int cur = 0;
    for (int it = 0; it < MITERS; ++it) {
        const int m0 = mbase + it * MT;

        // stage next tile into buf^1 (no conflict with buf[cur] readers)
        if (it + 1 < MITERS) {
            *(uint4*)(XmL[cur ^ 1] + xrow * 40 + xseg * 8) = xv;
            *(uint4*)(HtL[cur ^ 1] + hrow * 72 + hseg * 8) = hv;
            if (it + 2 < MITERS) {
                const int m2n = mbase + (it + 2) * MT;
                xv = *(const uint4*)(Xb + xbase + (size_t)(m2n + xrow) * DF + xseg * 8);
                hv = *(const uint4*)(HT + tbase + (size_t)hrow * NT + m2n + hseg * 8);
            }
        }

        // ---- scores: St[m][n] tiles; lane holds S[n=c][m = t4*16+q*4+r] ----
        const unsigned short* XmC = XmL[cur];
        if (m0 == n0) {
            #pragma unroll
            for (int t4 = 0; t4 < 4; ++t4) {
                const bf16x8 af = *(const bf16x8*)(XmC + (t4 * 16 + c) * 40 + q * 8);
                const f32x4 zero = {0.f, 0.f, 0.f, 0.f};
                f32x4 st = __builtin_amdgcn_mfma_f32_16x16x32_bf16(af, bfn, zero, 0, 0, 0);
                const int m2 = m0 + t4 * 16 + q * 4;
                float v0 = tanh_relu(st[0]); if (n_g == m2 + 0) v0 += SELF_EPS;
                float v1 = tanh_relu(st[1]); if (n_g == m2 + 1) v1 += SELF_EPS;
                float v2 = tanh_relu(st[2]); if (n_g == m2 + 2) v2 += SELF_EPS;
                float v3 = tanh_relu(st[3]); if (n_g == m2 + 3) v3 += SELF_EPS;
                unsigned p0 = pk2(v0, v1);
                unsigned p1 = pk2(v2, v3);
                *(uint2*)(SsW + c * 72 + t4 * 16 + q * 4) = make_uint2(p0, p1);
            }
        } else {
            #pragma unroll
            for (int t4 = 0; t4 < 4; ++t4) {
                const bf16x8 af = *(const bf16x8*)(XmC + (t4 * 16 + c) * 40 + q * 8);
                const f32x4 zero = {0.f, 0.f, 0.f, 0.f};
                f32x4 st = __builtin_amdgcn_mfma_f32_16x16x32_bf16(af, bfn, zero, 0, 0, 0);
                unsigned p0 = pk2(tanh_relu(st[0]), tanh_relu(st[1]));
                unsigned p1 = pk2(tanh_relu(st[2]), tanh_relu(st[3]));
                *(uint2*)(SsW + c * 72 + t4 * 16 + q * 4) = make_uint2(p0, p1);
            }
        }
        // cross-lane S visibility within the wave: drain LDS writes
        asm volatile("s_waitcnt lgkmcnt(0)" ::: "memory");

        // ---- agg: acc[n][d] += S[n][m] * H[m][d], K=64 in 2 chunks ----
        const unsigned short* HtC = HtL[cur];
        #pragma unroll
        for (int kc = 0; kc < 2; ++kc) {
            const bf16x8 sf = *(const bf16x8*)(SsW + c * 72 + kc * 32 + q * 8);
            // stream the A-layout fragment out for layer 2 (coalesced 16B/lane)
            *(uint4*)(Sgw + (size_t)(it * 2 + kc) * (64 * 8)) = __builtin_bit_cast(uint4, sf);
            const bf16x8 h0 = *(const bf16x8*)(HtC + c * 72 + kc * 32 + q * 8);
            const bf16x8 h1 = *(const bf16x8*)(HtC + (16 + c) * 72 + kc * 32 + q * 8);
            acc0 = __builtin_amdgcn_mfma_f32_16x16x32_bf16(sf, h0, acc0, 0, 0, 0);
            acc1 = __builtin_amdgcn_mfma_f32_16x16x32_bf16(sf, h1, acc1, 0, 0, 0);
        }

        __syncthreads();                       // buf^1 staged; cur readers done
        cur ^= 1;
    }

    float* ap = P + ((size_t)blockIdx.y * NB + b) * NT * DF
                  + (size_t)(n0 + w * 16 + q * 4) * DF + c;
    #pragma unroll
    for (int r = 0; r < 4; ++r) {
        ap[(size_t)r * DF] = acc0[r];
        ap[(size_t)r * DF + 16] = acc1[r];
    }
}

// ---------------------------------------------------------------------------
// layer-2 agg: NO score recompute — replay stored A-layout S fragments
// (reg-prefetched); double-buffered HT staging, 1 barrier/iter.
// ---------------------------------------------------------------------------
__global__ __launch_bounds__(256, 6)
void gsage_agg(const unsigned short* __restrict__ Sg,
               const unsigned short* __restrict__ HT,  // [B][32][NT] bf16
               float* __restrict__ P)                  // [MS][B][NT][32] fp32
{
    __shared__ unsigned short HtL[2][32 * 72];

    const int t = threadIdx.x;
    const int w = t >> 6, lane = t & 63;
    const int q = lane >> 4, c = lane & 15;
    const int n0 = blockIdx.x * TN;
    const int mbase = blockIdx.y * MROWS;
    const int b = blockIdx.z;
    const size_t tbase = (size_t)b * DF * NT;

    const int hrow = t >> 3, hseg = t & 7;

    // prologue: stage tile 0 into buf 0; prefetch tile 1 into regs
    uint4 hv = *(const uint4*)(HT + tbase + (size_t)hrow * NT + mbase + hseg * 8);
    *(uint4*)(HtL[0] + hrow * 72 + hseg * 8) = hv;
    hv = *(const uint4*)(HT + tbase + (size_t)hrow * NT + mbase + MT + hseg * 8);

    const unsigned short* Sp = Sg
        + ((((size_t)b * MS + blockIdx.y) * NBK + blockIdx.x) * 4 + w)
          * ((size_t)MITERS * 2 * 64 * 8)
        + (size_t)lane * 8;

    bf16x8 sf0 = *(const bf16x8*)(Sp);
    bf16x8 sf1 = *(const bf16x8*)(Sp + 64 * 8);

    f32x4 acc0 = {0.f, 0.f, 0.f, 0.f};
    f32x4 acc1 = {0.f, 0.f, 0.f, 0.f};

    __syncthreads();                           // buf0 staged

    int cur = 0;
    for (int it = 0; it < MITERS; ++it) {
        bf16x8 nsf0, nsf1;
        if (it + 1 < MITERS) {
            *(uint4*)(HtL[cur ^ 1] + hrow * 72 + hseg * 8) = hv;
            if (it + 2 < MITERS) {
                hv = *(const uint4*)(HT + tbase + (size_t)hrow * NT
                                     + (mbase + (it + 2) * MT) + hseg * 8);
            }
            nsf0 = *(const bf16x8*)(Sp + (size_t)((it + 1) * 2 + 0) * (64 * 8));
            nsf1 = *(const bf16x8*)(Sp + (size_t)((it + 1) * 2 + 1) * (64 * 8));
        }

        const unsigned short* HtC = HtL[cur];
        const bf16x8 h00 = *(const bf16x8*)(HtC + c * 72 + 0 * 32 + q * 8);
        const bf16x8 h01 = *(const bf16x8*)(HtC + (16 + c) * 72 + 0 * 32 + q * 8);
        acc0 = __builtin_amdgcn_mfma_f32_16x16x32_bf16(sf0, h00, acc0, 0, 0, 0);
        acc1 = __builtin_amdgcn_mfma_f32_16x16x32_bf16(sf0, h01, acc1, 0, 0, 0);
        const bf16x8 h10 = *(const bf16x8*)(HtC + c * 72 + 1 * 32 + q * 8);
        const bf16x8 h11 = *(const bf16x8*)(HtC + (16 + c) * 72 + 1 * 32 + q * 8);
        acc0 = __builtin_amdgcn_mfma_f32_16x16x32_bf16(sf1, h10, acc0, 0, 0, 0);
        acc1 = __builtin_amdgcn_mfma_f32_16x16x32_bf16(sf1, h11, acc1, 0, 0, 0);

        __syncthreads();                       // buf^1 staged; cur readers done
        cur ^= 1;
        if (it + 1 < MITERS) { sf0 = nsf0; sf1 = nsf1; }
    }

    float* ap = P + ((size_t)blockIdx.y * NB + b) * NT * DF
                  + (size_t)(n0 + w * 16 + q * 4) * DF + c;
    #pragma unroll
    for (int r = 0; r < 4; ++r) {
        ap[(size_t)r * DF] = acc0[r];
        ap[(size_t)r * DF + 16] = acc1[r];
    }
}

// ---------------------------------------------------------------------------
// epilogue: agg = sum of 8 m-slice partials; Hout = elu(Hin*Ws + agg*Wn + b);
// optionally emit Hout^T bf16.
// ---------------------------------------------------------------------------
__global__ __launch_bounds__(256, 4)
void gsage_epi(const float* __restrict__ Hin, const float* __restrict__ P,
               const float* __restrict__ Wsl, const float* __restrict__ Wnl,
               const float* __restrict__ bl,
               float* __restrict__ Hout, unsigned short* __restrict__ HTout)
{
    __shared__ float sW[32][33], sN[32][33], sH[32][36], sA[32][36], sT[32][33];
    const int t = threadIdx.x;
    const int n0 = blockIdx.x * 32;
    const int b = blockIdx.y;
    const int row = t >> 3, c4 = (t & 7) * 4;
    const size_t rb = ((size_t)(b * NT + n0 + row)) * DF + c4;
    const float4 hv = *(const float4*)(Hin + rb);
    const size_t pstride = (size_t)NB * NT * DF;
    float4 av = *(const float4*)(P + rb);
    #pragma unroll
    for (int s = 1; s < MS; ++s) {
        const float4 pv = *(const float4*)(P + (size_t)s * pstride + rb);
        av.x += pv.x; av.y += pv.y; av.z += pv.z; av.w += pv.w;
    }
    const float4 w0 = *(const float4*)(Wsl + row * DF + c4);
    const float4 w1 = *(const float4*)(Wnl + row * DF + c4);
    sH[row][c4+0]=hv.x; sH[row][c4+1]=hv.y; sH[row][c4+2]=hv.z; sH[row][c4+3]=hv.w;
    sA[row][c4+0]=av.x; sA[row][c4+1]=av.y; sA[row][c4+2]=av.z; sA[row][c4+3]=av.w;
    sW[row][c4+0]=w0.x; sW[row][c4+1]=w0.y; sW[row][c4+2]=w0.z; sW[row][c4+3]=w0.w;
    sN[row][c4+0]=w1.x; sN[row][c4+1]=w1.y; sN[row][c4+2]=w1.z; sN[row][c4+3]=w1.w;
    __syncthreads();

    float4 z = make_float4(bl[c4+0], bl[c4+1], bl[c4+2], bl[c4+3]);
    #pragma unroll
    for (int k = 0; k < DF; ++k) {
        const float hk = sH[row][k], ak = sA[row][k];
        z.x += hk * sW[k][c4+0] + ak * sN[k][c4+0];
        z.y += hk * sW[k][c4+1] + ak * sN[k][c4+1];
        z.z += hk * sW[k][c4+2] + ak * sN[k][c4+2];
        z.w += hk * sW[k][c4+3] + ak * sN[k][c4+3];
    }
    z.x = z.x > 0.f ? z.x : __expf(z.x) - 1.f;
    z.y = z.y > 0.f ? z.y : __expf(z.y) - 1.f;
    z.z = z.z > 0.f ? z.z : __expf(z.z) - 1.f;
    z.w = z.w > 0.f ? z.w : __expf(z.w) - 1.f;
    *(float4*)(Hout + rb) = z;

    if (HTout != nullptr) {
        sT[row][c4+0]=z.x; sT[row][c4+1]=z.y; sT[row][c4+2]=z.z; sT[row][c4+3]=z.w;
        __syncthreads();
        const int d = t >> 3, nq = (t & 7) * 4;
        unsigned q0 = pk2(sT[nq+0][d], sT[nq+1][d]);
        unsigned q1 = pk2(sT[nq+2][d], sT[nq+3][d]);
        *(uint2*)(HTout + ((size_t)(b * DF + d)) * NT + n0 + nq) = make_uint2(q0, q1);
    }
}

extern "C" void kernel_launch(void* const* d_in, const int* in_sizes, int n_in,
                              void* d_out, int out_size, void* d_ws, size_t ws_size,
                              hipStream_t stream) {
    const float* X  = (const float*)d_in[0];
    const float* Ws = (const float*)d_in[1];   // [2][32][32]
    const float* Wn = (const float*)d_in[2];   // [2][32][32]
    const float* bv = (const float*)d_in[3];   // [2][32]
    float* out = (float*)d_out;

    char* ws = (char*)d_ws;
    float* P  = (float*)ws;                                  // 10,485,760 B
    float* h1 = P + (size_t)MS * NB * NT * DF;               // 1,310,720 B
    unsigned short* Xb  = (unsigned short*)(ws + 11796480);  // 655,360 B
    unsigned short* XT  = Xb + (size_t)NB * NT * DF;         // 655,360 B
    unsigned short* H1T = XT + (size_t)NB * NT * DF;         // 655,360 B
    unsigned short* Sg  = H1T + (size_t)NB * NT * DF;        // 52,428,800 B

    prep<<<320, 256, 0, stream>>>(X, Xb, XT);

    dim3 g(NBK, MS, NB);   // 40 x 8 x 4 = 1280 blocks
    gsage_main<<<g, 256, 0, stream>>>(Xb, XT, P, Sg);
    gsage_epi<<<dim3(NT / 32, NB), 256, 0, stream>>>(X, P, Ws, Wn, bv, h1, H1T);
    gsage_agg<<<g, 256, 0, stream>>>(Sg, H1T, P);
    gsage_epi<<<dim3(NT / 32, NB), 256, 0, stream>>>(h1, P, Ws + DF * DF, Wn + DF * DF,
                                                     bv + DF, out, nullptr);
}